// Round 7
// baseline (3420.404 us; speedup 1.0000x reference)
//
#include <hip/hip_runtime.h>

#define EPS_F 1.1920929e-07f

typedef __attribute__((ext_vector_type(8))) short bf16x8;
typedef __attribute__((ext_vector_type(4))) float f32x4;

__device__ __forceinline__ unsigned short f2bf(float f) {
    unsigned u = __float_as_uint(f);
    unsigned r = (u + 0x7FFFu + ((u >> 16) & 1u)) >> 16;
    return (unsigned short)r;
}

__device__ __forceinline__ float dot4(float4 a, float4 b) {
    return fmaf(a.x, b.x, fmaf(a.y, b.y, fmaf(a.z, b.z, a.w * b.w)));
}

__device__ __forceinline__ float gelu_exact(float v) {
    return 0.5f * v * (1.f + erff(v * 0.70710678118654752440f));
}

// ---------------- embedding ----------------
__global__ __launch_bounds__(256) void k_embed(const int* __restrict__ tok,
        const float* __restrict__ ew, float* __restrict__ x) {
    int row = blockIdx.x, t = threadIdx.x;
    int tk = tok[row];
    float4 v = *(const float4*)(&ew[(size_t)tk * 1024 + t * 4]);
    *(float4*)(&x[(size_t)row * 1024 + t * 4]) = v;
}

// ---------------- K1: rotation + router partial sums ----------------
__global__ __launch_bounds__(256) void k1_rot(const float* __restrict__ x, float* __restrict__ xn,
        const float* __restrict__ ang, const int* __restrict__ pI, const int* __restrict__ pJ,
        const float* __restrict__ rw, float* __restrict__ msum) {
    __shared__ float rs[1024];
    __shared__ float red[4][4];
    int row = blockIdx.x;
    int b = row >> 10;
    int t = threadIdx.x;
    float4 v = *(const float4*)(&x[(size_t)row * 1024 + t * 4]);
    *(float4*)(&rs[t * 4]) = v;
    __syncthreads();
    if (t < 32) {
        int ii = pI[t], jj = pJ[t];
        float xi = rs[ii], xj = rs[jj];
        float a = ang[t];
        float ca = cosf(a), sa = sinf(a);
        rs[ii] = xi * ca - xj * sa;
        rs[jj] = xi * sa + xj * ca;
    }
    __syncthreads();
    float4 wv = *(const float4*)(&rs[t * 4]);
    *(float4*)(&xn[(size_t)row * 1024 + t * 4]) = wv;
    float4 q0 = *(const float4*)(&rw[0 * 1024 + t * 4]);
    float4 q1 = *(const float4*)(&rw[1 * 1024 + t * 4]);
    float4 q2 = *(const float4*)(&rw[2 * 1024 + t * 4]);
    float4 q3 = *(const float4*)(&rw[3 * 1024 + t * 4]);
    float r0 = dot4(wv, q0), r1 = dot4(wv, q1), r2 = dot4(wv, q2), r3 = dot4(wv, q3);
    for (int off = 32; off >= 1; off >>= 1) {
        r0 += __shfl_down(r0, off);
        r1 += __shfl_down(r1, off);
        r2 += __shfl_down(r2, off);
        r3 += __shfl_down(r3, off);
    }
    int lane = t & 63, wid = t >> 6;
    if (lane == 0) { red[wid][0] = r0; red[wid][1] = r1; red[wid][2] = r2; red[wid][3] = r3; }
    __syncthreads();
    if (t < 4) {
        float s = red[0][t] + red[1][t] + red[2][t] + red[3][t];
        atomicAdd(&msum[b * 4 + t], s);
    }
}

// ---------------- kA: fused gamma/beta + MLP1(gelu) + MLP2(silu) + rmsnorm + x update ----------------
// 4 rows per block, 256 threads.
__global__ __launch_bounds__(256) void kA_cycle(const float* __restrict__ xn,
        const float* __restrict__ msum, const float* __restrict__ msc,
        const float* __restrict__ msh, const float* __restrict__ w1,
        const float* __restrict__ b1, const float* __restrict__ w2,
        const float* __restrict__ b2, const float* __restrict__ nw,
        const float* __restrict__ csp, float* __restrict__ x) {
    __shared__ float xm[4][1024];
    __shared__ float hs[4][32];
    __shared__ float red[4][4];
    __shared__ float bcs[4];
    int row0 = blockIdx.x * 4;
    int b = row0 >> 10;
    int t = threadIdx.x;
    const float invS = 1.f / 1024.f;
    // router softmax (redundant per thread; trivial)
    float l0 = msum[b * 4 + 0] * invS;
    float l1 = msum[b * 4 + 1] * invS;
    float l2 = msum[b * 4 + 2] * invS;
    float l3 = msum[b * 4 + 3] * invS;
    float mx = fmaxf(fmaxf(l0, l1), fmaxf(l2, l3));
    float e0 = expf(l0 - mx), e1 = expf(l1 - mx), e2 = expf(l2 - mx), e3 = expf(l3 - mx);
    float inv = 1.f / (e0 + e1 + e2 + e3);
    float w0 = e0 * inv, w1w = e1 * inv, w2w = e2 * inv, w3 = e3 * inv;
    // gamma/beta for this thread's 4 contiguous dims
    float4 g, be;
    {
        float4 a0 = *(const float4*)(&msc[0 * 1024 + t * 4]);
        float4 a1 = *(const float4*)(&msc[1 * 1024 + t * 4]);
        float4 a2 = *(const float4*)(&msc[2 * 1024 + t * 4]);
        float4 a3 = *(const float4*)(&msc[3 * 1024 + t * 4]);
        g.x = w0 * a0.x + w1w * a1.x + w2w * a2.x + w3 * a3.x;
        g.y = w0 * a0.y + w1w * a1.y + w2w * a2.y + w3 * a3.y;
        g.z = w0 * a0.z + w1w * a1.z + w2w * a2.z + w3 * a3.z;
        g.w = w0 * a0.w + w1w * a1.w + w2w * a2.w + w3 * a3.w;
        float4 s0 = *(const float4*)(&msh[0 * 1024 + t * 4]);
        float4 s1 = *(const float4*)(&msh[1 * 1024 + t * 4]);
        float4 s2 = *(const float4*)(&msh[2 * 1024 + t * 4]);
        float4 s3 = *(const float4*)(&msh[3 * 1024 + t * 4]);
        be.x = w0 * s0.x + w1w * s1.x + w2w * s2.x + w3 * s3.x;
        be.y = w0 * s0.y + w1w * s1.y + w2w * s2.y + w3 * s3.y;
        be.z = w0 * s0.z + w1w * s1.z + w2w * s2.z + w3 * s3.z;
        be.w = w0 * s0.w + w1w * s1.w + w2w * s2.w + w3 * s3.w;
    }
    // stage x_mod = xn*gamma + beta
#pragma unroll
    for (int r = 0; r < 4; ++r) {
        float4 xv = *(const float4*)(&xn[(size_t)(row0 + r) * 1024 + t * 4]);
        float4 m;
        m.x = fmaf(xv.x, g.x, be.x);
        m.y = fmaf(xv.y, g.y, be.y);
        m.z = fmaf(xv.z, g.z, be.z);
        m.w = fmaf(xv.w, g.w, be.w);
        *(float4*)(&xm[r][t * 4]) = m;
    }
    __syncthreads();
    // MLP1: h[r][p] = gelu(xm[r] . w1[p] + b1[p]);  p = t>>3, 8 lanes/p
    {
        int p = t >> 3, g8 = t & 7;
        const float* w1p = w1 + p * 1024;
        float a0 = 0.f, a1 = 0.f, a2 = 0.f, a3 = 0.f;
#pragma unroll 4
        for (int j = 0; j < 32; ++j) {
            int col = j * 32 + g8 * 4;
            float4 wv = *(const float4*)(&w1p[col]);
            float4 x0 = *(const float4*)(&xm[0][col]);
            float4 x1 = *(const float4*)(&xm[1][col]);
            float4 x2 = *(const float4*)(&xm[2][col]);
            float4 x3 = *(const float4*)(&xm[3][col]);
            a0 += dot4(x0, wv); a1 += dot4(x1, wv); a2 += dot4(x2, wv); a3 += dot4(x3, wv);
        }
        a0 += __shfl_xor(a0, 1); a0 += __shfl_xor(a0, 2); a0 += __shfl_xor(a0, 4);
        a1 += __shfl_xor(a1, 1); a1 += __shfl_xor(a1, 2); a1 += __shfl_xor(a1, 4);
        a2 += __shfl_xor(a2, 1); a2 += __shfl_xor(a2, 2); a2 += __shfl_xor(a2, 4);
        a3 += __shfl_xor(a3, 1); a3 += __shfl_xor(a3, 2); a3 += __shfl_xor(a3, 4);
        if (g8 == 0) {
            float bb = b1[p];
            hs[0][p] = gelu_exact(a0 + bb);
            hs[1][p] = gelu_exact(a1 + bb);
            hs[2][p] = gelu_exact(a2 + bb);
            hs[3][p] = gelu_exact(a3 + bb);
        }
    }
    __syncthreads();
    // MLP2 + silu + u = xo - x; each thread owns dims {t, t+256, t+512, t+768}
    float cs = csp[0];
    float u[4][4], xvv[4][4];
    float sacc0 = 0.f, sacc1 = 0.f, sacc2 = 0.f, sacc3 = 0.f;
#pragma unroll
    for (int q = 0; q < 4; ++q) {
        int d = t + 256 * q;
        float4 wv[8];
        const float* w2p = w2 + d * 32;
#pragma unroll
        for (int k = 0; k < 8; ++k) wv[k] = *(const float4*)(&w2p[k * 4]);
        float b2v = b2[d];
#pragma unroll
        for (int r = 0; r < 4; ++r) {
            float acc = b2v;
            const float4* hp = (const float4*)(&hs[r][0]);
#pragma unroll
            for (int k = 0; k < 8; ++k) acc += dot4(wv[k], hp[k]);
            float xo = acc / (1.f + expf(-acc));  // silu
            float xl = x[(size_t)(row0 + r) * 1024 + d];
            float uu = xo - xl;
            u[r][q] = uu; xvv[r][q] = xl;
            if (r == 0) sacc0 += uu * uu;
            else if (r == 1) sacc1 += uu * uu;
            else if (r == 2) sacc2 += uu * uu;
            else sacc3 += uu * uu;
        }
    }
    for (int off = 32; off >= 1; off >>= 1) {
        sacc0 += __shfl_down(sacc0, off);
        sacc1 += __shfl_down(sacc1, off);
        sacc2 += __shfl_down(sacc2, off);
        sacc3 += __shfl_down(sacc3, off);
    }
    int lane = t & 63, wid = t >> 6;
    if (lane == 0) { red[wid][0] = sacc0; red[wid][1] = sacc1; red[wid][2] = sacc2; red[wid][3] = sacc3; }
    __syncthreads();
    if (t < 4) {
        float tot = red[0][t] + red[1][t] + red[2][t] + red[3][t];
        bcs[t] = rsqrtf(tot * invS + EPS_F);
    }
    __syncthreads();
#pragma unroll
    for (int q = 0; q < 4; ++q) {
        int d = t + 256 * q;
        float nwv = nw[d];
#pragma unroll
        for (int r = 0; r < 4; ++r)
            x[(size_t)(row0 + r) * 1024 + d] = xvv[r][q] + cs * 0.5f * u[r][q] * bcs[r] * nwv;
    }
}

// ---------------- EMA scan: chunked linear recurrence (32 chunks x 32 steps) ----------------
__global__ __launch_bounds__(256) void s1_local(const float* __restrict__ x,
        const float* __restrict__ sd, float* __restrict__ causal, float* __restrict__ carry) {
    int e = blockIdx.x * 256 + threadIdx.x;  // 0..65535
    int d = e & 1023, ch = (e >> 10) & 31, b = e >> 15;
    float dec = 1.f / (1.f + expf(-sd[0]));
    float omd = 1.f - dec;
    size_t base = ((size_t)(b * 1024 + ch * 32)) * 1024 + d;
    float st = 0.f;
#pragma unroll 8
    for (int j = 0; j < 32; ++j) {
        float xv = x[base + (size_t)j * 1024];
        st = fmaf(dec, st, omd * xv);
        causal[base + (size_t)j * 1024] = st;
    }
    carry[(size_t)(b * 32 + ch) * 1024 + d] = st;
}

__global__ __launch_bounds__(256) void s2_prefix(const float* __restrict__ sd,
        const float* __restrict__ carry, float* __restrict__ P) {
    int e = blockIdx.x * 256 + threadIdx.x;  // 0..2047
    int d = e & 1023, b = e >> 10;
    float dec = 1.f / (1.f + expf(-sd[0]));
    float dl = powf(dec, 32.f);
    float st = 0.f;
    for (int ch = 0; ch < 32; ++ch) {
        size_t o = (size_t)(b * 32 + ch) * 1024 + d;
        P[o] = st;
        st = fmaf(dl, st, carry[o]);
    }
}

__global__ __launch_bounds__(256) void s3_apply(const float* __restrict__ causal,
        const float* __restrict__ P, const float* __restrict__ sd,
        unsigned short* __restrict__ cbf) {
    int idx = blockIdx.x * 256 + threadIdx.x;  // 0..2M-1
    int d = idx & 1023, s = (idx >> 10) & 1023, b = idx >> 20;
    int j = s & 31, ch = s >> 5;
    float dec = 1.f / (1.f + expf(-sd[0]));
    float val = causal[idx] + powf(dec, (float)(j + 1)) * P[(size_t)(b * 32 + ch) * 1024 + d];
    cbf[idx] = f2bf(val);
}

// ---------------- final rmsnorm -> bf16 A ----------------
__global__ __launch_bounds__(256) void k_fnorm(const float* __restrict__ x,
        const float* __restrict__ onw, unsigned short* __restrict__ abf) {
    __shared__ float red[4];
    __shared__ float bc;
    int row = blockIdx.x, t = threadIdx.x;
    float4 v = *(const float4*)(&x[(size_t)row * 1024 + t * 4]);
    float s = dot4(v, v);
    for (int off = 32; off >= 1; off >>= 1) s += __shfl_down(s, off);
    if ((t & 63) == 0) red[t >> 6] = s;
    __syncthreads();
    if (t == 0) bc = rsqrtf((red[0] + red[1] + red[2] + red[3]) * (1.f / 1024.f) + EPS_F);
    __syncthreads();
    float sc = bc;
    float4 w = *(const float4*)(&onw[t * 4]);
    ushort4 o;
    o.x = f2bf(v.x * sc * w.x);
    o.y = f2bf(v.y * sc * w.y);
    o.z = f2bf(v.z * sc * w.z);
    o.w = f2bf(v.w * sc * w.w);
    *(ushort4*)(&abf[(size_t)row * 1024 + t * 4]) = o;
}

// ---------------- bf16 MFMA NT GEMM: C[m][n] (+)= sum_k A[m][k]*bf16(Bf[n][k]) ----------------
// A bf16 row-major [M][K]; Bf fp32 row-major [N][K] (converted during staging); C fp32 [M][ldc].
// 128x128 tile, BK=64, 256 threads = 4 waves (2x2), each wave 64x64 via 4x4 frags of 16x16x32.
// Grid: blockIdx.x = m-tile (FAST, small), blockIdx.y = n-tile -> consecutive blocks share B-tile,
// W streams once from HBM instead of once per m-tile.
template <int ACC>
__global__ __launch_bounds__(256) void gemm_bf16_nt(const unsigned short* __restrict__ A,
        const float* __restrict__ Bf, float* __restrict__ C,
        int M, int N, int K, int ldc) {
    __shared__ unsigned short As[128][72];
    __shared__ unsigned short Bs[128][72];
    int m0 = blockIdx.x * 128;
    int n0 = blockIdx.y * 128;
    int t = threadIdx.x;
    int lane = t & 63, wid = t >> 6;
    int wr = wid >> 1, wc = wid & 1;
    f32x4 acc[4][4];
#pragma unroll
    for (int m = 0; m < 4; ++m)
#pragma unroll
        for (int n = 0; n < 4; ++n) acc[m][n] = (f32x4){0.f, 0.f, 0.f, 0.f};

    for (int k0 = 0; k0 < K; k0 += 64) {
        {   // stage A: 128x64 bf16, 16B per thread per pass
            int row = t >> 3;
            int col = (t & 7) * 8;
#pragma unroll
            for (int pass = 0; pass < 4; ++pass) {
                int r = row + pass * 32;
                int4 v = *(const int4*)(&A[(size_t)(m0 + r) * K + k0 + col]);
                *(int4*)(&As[r][col]) = v;
            }
        }
        {   // stage B: 128x64 from fp32 with N guard, convert to bf16
            int row = t >> 4;
            int col = (t & 15) * 4;
#pragma unroll
            for (int pass = 0; pass < 8; ++pass) {
                int r = row + pass * 16;
                int n = n0 + r;
                float4 v = make_float4(0.f, 0.f, 0.f, 0.f);
                if (n < N) v = *(const float4*)(&Bf[(size_t)n * K + k0 + col]);
                ushort4 hx;
                hx.x = f2bf(v.x); hx.y = f2bf(v.y); hx.z = f2bf(v.z); hx.w = f2bf(v.w);
                *(ushort4*)(&Bs[r][col]) = hx;
            }
        }
        __syncthreads();
#pragma unroll
        for (int kk = 0; kk < 64; kk += 32) {
            bf16x8 a[4], b[4];
#pragma unroll
            for (int m = 0; m < 4; ++m)
                a[m] = *(const bf16x8*)(&As[wr * 64 + m * 16 + (lane & 15)][kk + (lane >> 4) * 8]);
#pragma unroll
            for (int n = 0; n < 4; ++n)
                b[n] = *(const bf16x8*)(&Bs[wc * 64 + n * 16 + (lane & 15)][kk + (lane >> 4) * 8]);
#pragma unroll
            for (int m = 0; m < 4; ++m)
#pragma unroll
                for (int n = 0; n < 4; ++n)
                    acc[m][n] = __builtin_amdgcn_mfma_f32_16x16x32_bf16(a[m], b[n], acc[m][n], 0, 0, 0);
        }
        __syncthreads();
    }
    // epilogue: C/D layout col=lane&15, row=(lane>>4)*4+reg
#pragma unroll
    for (int m = 0; m < 4; ++m) {
        int rbase = m0 + wr * 64 + m * 16 + (lane >> 4) * 4;
#pragma unroll
        for (int n = 0; n < 4; ++n) {
            int col = n0 + wc * 64 + n * 16 + (lane & 15);
            if (col < N) {
#pragma unroll
                for (int j = 0; j < 4; ++j) {
                    size_t idx = (size_t)(rbase + j) * ldc + col;
                    if (ACC) C[idx] += acc[m][n][j];
                    else C[idx] = acc[m][n][j];
                }
            }
        }
    }
}

// ---------------- host launcher ----------------
extern "C" void kernel_launch(void* const* d_in, const int* in_sizes, int n_in,
                              void* d_out, int out_size, void* d_ws, size_t ws_size,
                              hipStream_t stream) {
    const int*   tokens      = (const int*)d_in[0];
    const float* embed_w     = (const float*)d_in[1];
    const float* angles      = (const float*)d_in[2];
    const int*   plane_i     = (const int*)d_in[3];
    const int*   plane_j     = (const int*)d_in[4];
    const float* mode_scales = (const float*)d_in[5];
    const float* mode_shifts = (const float*)d_in[6];
    const float* router_w    = (const float*)d_in[7];
    const float* wg1_w       = (const float*)d_in[8];
    const float* wg1_b       = (const float*)d_in[9];
    const float* wg2_w       = (const float*)d_in[10];
    const float* wg2_b       = (const float*)d_in[11];
    const float* cyc_norm_w  = (const float*)d_in[12];
    const float* scan_decay  = (const float*)d_in[13];
    const float* scan_gate_w = (const float*)d_in[14];
    const float* cycle_scale = (const float*)d_in[15];
    const float* out_norm_w  = (const float*)d_in[16];
    const float* lm_head_w   = (const float*)d_in[17];
    float* out = (float*)d_out;

    char* wsb = (char*)d_ws;
    float* x     = (float*)(wsb + 0);                                // 8 MB
    float* xn    = (float*)(wsb + (8u << 20));                       // 8 MB (reused as causal)
    unsigned short* cbf = (unsigned short*)(wsb + (16u << 20));      // 4 MB causal bf16
    unsigned short* abf = (unsigned short*)(wsb + (20u << 20));      // 4 MB final-A bf16
    float* carry = (float*)(wsb + (24u << 20));                      // 256 KB
    float* Pbuf  = (float*)(wsb + (24u << 20) + (256u << 10));       // 256 KB
    float* msum  = (float*)(wsb + (24u << 20) + (512u << 10));       // 28*8 floats

    hipMemsetAsync(msum, 0, 28 * 8 * sizeof(float), stream);
    k_embed<<<2048, 256, 0, stream>>>(tokens, embed_w, x);

    for (int i = 0; i < 28; ++i) {
        int c = i & 3;
        k1_rot<<<2048, 256, 0, stream>>>(x, xn, angles + c * 32, plane_i + c * 32,
                                         plane_j + c * 32, router_w + c * 4 * 1024, msum + i * 8);
        kA_cycle<<<512, 256, 0, stream>>>(xn, msum + i * 8, mode_scales + c * 4 * 1024,
                                          mode_shifts + c * 4 * 1024,
                                          wg1_w + c * 32 * 1024, wg1_b + c * 32,
                                          wg2_w + c * 1024 * 32, wg2_b + c * 1024,
                                          cyc_norm_w + c * 1024, cycle_scale + i, x);
        if (i % 7 == 6) {
            s1_local<<<256, 256, 0, stream>>>(x, scan_decay, xn, carry);
            s2_prefix<<<8, 256, 0, stream>>>(scan_decay, carry, Pbuf);
            s3_apply<<<8192, 256, 0, stream>>>(xn, Pbuf, scan_decay, cbf);
            gemm_bf16_nt<1><<<dim3(16, 8), 256, 0, stream>>>(cbf, scan_gate_w, x,
                                                             2048, 1024, 1024, 1024);
        }
    }

    k_fnorm<<<2048, 256, 0, stream>>>(x, out_norm_w, abf);
    gemm_bf16_nt<0><<<dim3(16, 393), 256, 0, stream>>>(abf, lm_head_w, out,
                                                       2048, 50257, 1024, 50257);
}